// Round 1
// baseline (141.435 us; speedup 1.0000x reference)
//
#include <hip/hip_runtime.h>
#include <math.h>

// ---------------------------------------------------------------------------
// QuantumResidualRegressor: enc-MLP -> 6-qubit circuit sim -> head-MLP -> +baseline
// One thread per sample; full 64-amp complex state in registers, fully unrolled.
// ---------------------------------------------------------------------------

#define NQ 6

// LDS layout (float offsets)
#define OW1   0      // 512  enc_w1 [32][16]
#define OB1   512    // 16   enc_b1
#define OW2   528    // 96   enc_w2 [16][6]
#define OB2   624    // 6    enc_b2
#define OHW1  632    // 96   head_w1 [6][16]   (byte off 2528, 16B aligned)
#define OHB1  728    // 16   head_b1
#define OHW2  744    // 16   head_w2 [16][1]
#define OHB2  760    // 1    head_b2
#define OCW   764    // 18   cos(q_weights*0.5)
#define OSW   782    // 18   sin(q_weights*0.5)
#define LDSF  800

__global__ __launch_bounds__(256, 2)
void qrr_kernel(const float* __restrict__ features,
                const float* __restrict__ baseline,
                const float* __restrict__ enc_w1,
                const float* __restrict__ enc_b1,
                const float* __restrict__ enc_w2,
                const float* __restrict__ enc_b2,
                const float* __restrict__ q_weights,
                const float* __restrict__ head_w1,
                const float* __restrict__ head_b1,
                const float* __restrict__ head_w2,
                const float* __restrict__ head_b2,
                float* __restrict__ out,
                int n)
{
    __shared__ __align__(16) float lds[LDSF];
    const int tid = threadIdx.x;

    // ---- cooperative weight preload (different thread ranges in parallel) ----
    for (int k = tid; k < 512; k += 256) lds[OW1 + k] = enc_w1[k];
    if (tid < 16)                 lds[OB1 + tid] = enc_b1[tid];
    if (tid < 96)                 lds[OW2 + tid] = enc_w2[tid];
    if (tid < 6)                  lds[OB2 + tid] = enc_b2[tid];
    if (tid >= 128 && tid < 224)  lds[OHW1 + tid - 128] = head_w1[tid - 128];
    if (tid >= 224 && tid < 240)  lds[OHB1 + tid - 224] = head_b1[tid - 224];
    if (tid >= 240 && tid < 256)  lds[OHW2 + tid - 240] = head_w2[tid - 240];
    if (tid == 127)               lds[OHB2] = head_b2[0];
    if (tid >= 96 && tid < 114) {                       // 18 rotation angles
        int k = tid - 96;
        float hw = q_weights[k] * 0.5f;
        lds[OCW + k] = cosf(hw);
        lds[OSW + k] = sinf(hw);
    }
    __syncthreads();

    const int b = blockIdx.x * 256 + tid;
    if (b >= n) return;

    // ---- load features (32 floats, 8x float4) ----
    float f[32];
    {
        const float4* fp = reinterpret_cast<const float4*>(features + (size_t)b * 32);
        #pragma unroll
        for (int k = 0; k < 8; ++k) {
            float4 v = fp[k];
            f[4*k+0] = v.x; f[4*k+1] = v.y; f[4*k+2] = v.z; f[4*k+3] = v.w;
        }
    }

    // ---- encoder layer 1: [32]->[16], exact GELU ----
    float h[16];
    #pragma unroll
    for (int o = 0; o < 16; ++o) h[o] = lds[OB1 + o];
    #pragma unroll
    for (int i = 0; i < 32; ++i) {
        const float fi = f[i];
        const float4* w = reinterpret_cast<const float4*>(&lds[OW1 + i * 16]);
        #pragma unroll
        for (int o4 = 0; o4 < 4; ++o4) {
            float4 wv = w[o4];
            h[o4*4+0] = fmaf(fi, wv.x, h[o4*4+0]);
            h[o4*4+1] = fmaf(fi, wv.y, h[o4*4+1]);
            h[o4*4+2] = fmaf(fi, wv.z, h[o4*4+2]);
            h[o4*4+3] = fmaf(fi, wv.w, h[o4*4+3]);
        }
    }
    #pragma unroll
    for (int o = 0; o < 16; ++o) {
        float x = h[o];
        h[o] = 0.5f * x * (1.0f + erff(x * 0.70710678118654752f));
    }

    // ---- encoder layer 2: [16]->[6], tanh -> angles ----
    float ang[6];
    #pragma unroll
    for (int o = 0; o < 6; ++o) {
        float a = lds[OB2 + o];
        #pragma unroll
        for (int i = 0; i < 16; ++i)
            a = fmaf(h[i], lds[OW2 + i * 6 + o], a);
        ang[o] = tanhf(a);
    }

    // ---- quantum circuit ----
    // flat amp index: qubit q <-> bit (5-q)  (qubit 0 most significant)
    float c6[6], s6[6];
    #pragma unroll
    for (int q = 0; q < 6; ++q) {
        float half = ang[q] * 0.5f;
        c6[q] = __cosf(half);
        s6[q] = __sinf(half);
    }

    // RY embedding from |0..0>: amp[j] = prod_q (bit_q ? s : c). Real state.
    float sr[64], si[64];
    sr[0] = 1.0f;
    #pragma unroll
    for (int qq = 0; qq < 6; ++qq) {        // process qubit 5-qq (stride 1<<qq)
        const int q = 5 - qq;
        const int len = 1 << qq;
        #pragma unroll
        for (int j = 0; j < len; ++j) {
            float v = sr[j];
            sr[j + len] = v * s6[q];
            sr[j]       = v * c6[q];
        }
    }
    #pragma unroll
    for (int j = 0; j < 64; ++j) si[j] = 0.0f;

    // entangler layers: RX on each wire then CNOT ring
    #pragma unroll
    for (int l = 0; l < 3; ++l) {
        #pragma unroll
        for (int q = 0; q < 6; ++q) {
            const float cw = lds[OCW + l * 6 + q];
            const float sw = lds[OSW + l * 6 + q];
            const int m = 1 << (5 - q);
            #pragma unroll
            for (int j = 0; j < 64; ++j) {
                if (j & m) continue;        // handle pair (j, j|m) once
                const int k = j | m;
                float r0 = sr[j], i0 = si[j], r1 = sr[k], i1 = si[k];
                // RX: a0' = cw*a0 - i*sw*a1 ; a1' = -i*sw*a0 + cw*a1
                sr[j] = fmaf(cw, r0,  sw * i1);
                si[j] = fmaf(cw, i0, -sw * r1);
                sr[k] = fmaf(cw, r1,  sw * i0);
                si[k] = fmaf(cw, i1, -sw * r0);
            }
        }
        // CNOT ring: control c, target (c+1)%6 — pure register permutation
        #pragma unroll
        for (int c = 0; c < 6; ++c) {
            const int t = (c + 1) % 6;
            const int cm = 1 << (5 - c);
            const int tm = 1 << (5 - t);
            #pragma unroll
            for (int j = 0; j < 64; ++j) {
                if ((j & cm) && !(j & tm)) {
                    const int k = j | tm;
                    float tr = sr[j]; sr[j] = sr[k]; sr[k] = tr;
                    float ti = si[j]; si[j] = si[k]; si[k] = ti;
                }
            }
        }
    }

    // ---- PauliZ expvals, shared fold tree ----
    float p[64];
    #pragma unroll
    for (int j = 0; j < 64; ++j) p[j] = fmaf(sr[j], sr[j], si[j] * si[j]);

    float z[6];
    #pragma unroll
    for (int qq = 0; qq < 6; ++qq) {        // qubit 5-qq differs in adjacent idx
        const int q = 5 - qq;
        const int half = 32 >> qq;
        float acc = 0.0f;
        #pragma unroll
        for (int k = 0; k < half; ++k) acc += p[2*k] - p[2*k+1];
        z[q] = acc;
        #pragma unroll
        for (int k = 0; k < half; ++k) p[k] = p[2*k] + p[2*k+1];
    }

    // ---- head: [6]->[16] GELU ->[1] ----
    float hh[16];
    #pragma unroll
    for (int o = 0; o < 16; ++o) hh[o] = lds[OHB1 + o];
    #pragma unroll
    for (int i = 0; i < 6; ++i) {
        const float zi = z[i];
        const float4* w = reinterpret_cast<const float4*>(&lds[OHW1 + i * 16]);
        #pragma unroll
        for (int o4 = 0; o4 < 4; ++o4) {
            float4 wv = w[o4];
            hh[o4*4+0] = fmaf(zi, wv.x, hh[o4*4+0]);
            hh[o4*4+1] = fmaf(zi, wv.y, hh[o4*4+1]);
            hh[o4*4+2] = fmaf(zi, wv.z, hh[o4*4+2]);
            hh[o4*4+3] = fmaf(zi, wv.w, hh[o4*4+3]);
        }
    }
    float r = lds[OHB2];
    #pragma unroll
    for (int o = 0; o < 16; ++o) {
        float x = hh[o];
        x = 0.5f * x * (1.0f + erff(x * 0.70710678118654752f));
        r = fmaf(x, lds[OHW2 + o], r);
    }

    out[b] = baseline[b] + r;
}

extern "C" void kernel_launch(void* const* d_in, const int* in_sizes, int n_in,
                              void* d_out, int out_size, void* d_ws, size_t ws_size,
                              hipStream_t stream) {
    const float* features = (const float*)d_in[0];
    const float* baseline = (const float*)d_in[1];
    const float* enc_w1   = (const float*)d_in[2];
    const float* enc_b1   = (const float*)d_in[3];
    const float* enc_w2   = (const float*)d_in[4];
    const float* enc_b2   = (const float*)d_in[5];
    const float* q_weights= (const float*)d_in[6];
    const float* head_w1  = (const float*)d_in[7];
    const float* head_b1  = (const float*)d_in[8];
    const float* head_w2  = (const float*)d_in[9];
    const float* head_b2  = (const float*)d_in[10];
    float* out = (float*)d_out;

    const int n = in_sizes[0] / 32;          // B
    const int block = 256;
    const int grid = (n + block - 1) / block;
    qrr_kernel<<<grid, block, 0, stream>>>(features, baseline,
                                           enc_w1, enc_b1, enc_w2, enc_b2,
                                           q_weights, head_w1, head_b1,
                                           head_w2, head_b2, out, n);
}

// Round 2
// 28.794 us; speedup vs baseline: 4.9120x; 4.9120x over previous
//
#include <hip/hip_runtime.h>
#include <math.h>

// ---------------------------------------------------------------------------
// QuantumResidualRegressor: enc-MLP -> 6-qubit circuit sim -> head-MLP -> +baseline
// One thread per sample; full 64-amp complex state in registers, fully unrolled.
// R2: force high-VGPR allocation (waves_per_eu 1..2) to kill scratch spills;
//     fast tanh-form GELU / exp2-based tanh (threshold is 0.09, errors ~1e-3).
// ---------------------------------------------------------------------------

// LDS layout (float offsets)
#define OW1   0      // 512  enc_w1 [32][16]
#define OB1   512    // 16   enc_b1
#define OW2   528    // 96   enc_w2 [16][6]
#define OB2   624    // 6    enc_b2
#define OHW1  632    // 96   head_w1 [6][16]
#define OHB1  728    // 16   head_b1
#define OHW2  744    // 16   head_w2 [16][1]
#define OHB2  760    // 1    head_b2
#define OCW   764    // 18   cos(q_weights*0.5)
#define OSW   782    // 18   sin(q_weights*0.5)
#define LDSF  800

__device__ __forceinline__ float fast_tanh(float x) {
    // tanh(x) = 1 - 2/(1+e^{2x}); exact limits at +-inf, no branches
    float e = __expf(2.0f * x);
    return 1.0f - 2.0f / (1.0f + e);
}

__device__ __forceinline__ float fast_gelu(float x) {
    // tanh-form GELU, |err| < ~3e-3 absolute — threshold is 9.06e-2
    float x3 = x * x * x;
    float t  = fast_tanh(fmaf(0.044715f, x3, x) * 0.7978845608028654f);
    return 0.5f * x * (1.0f + t);
}

__global__ __launch_bounds__(256) __attribute__((amdgpu_waves_per_eu(1, 2)))
void qrr_kernel(const float* __restrict__ features,
                const float* __restrict__ baseline,
                const float* __restrict__ enc_w1,
                const float* __restrict__ enc_b1,
                const float* __restrict__ enc_w2,
                const float* __restrict__ enc_b2,
                const float* __restrict__ q_weights,
                const float* __restrict__ head_w1,
                const float* __restrict__ head_b1,
                const float* __restrict__ head_w2,
                const float* __restrict__ head_b2,
                float* __restrict__ out,
                int n)
{
    __shared__ __align__(16) float lds[LDSF];
    const int tid = threadIdx.x;

    // ---- cooperative weight preload (disjoint thread ranges in parallel) ----
    for (int k = tid; k < 512; k += 256) lds[OW1 + k] = enc_w1[k];
    if (tid < 16)                 lds[OB1 + tid] = enc_b1[tid];
    if (tid < 96)                 lds[OW2 + tid] = enc_w2[tid];
    if (tid < 6)                  lds[OB2 + tid] = enc_b2[tid];
    if (tid >= 128 && tid < 224)  lds[OHW1 + tid - 128] = head_w1[tid - 128];
    if (tid >= 224 && tid < 240)  lds[OHB1 + tid - 224] = head_b1[tid - 224];
    if (tid >= 240 && tid < 256)  lds[OHW2 + tid - 240] = head_w2[tid - 240];
    if (tid == 127)               lds[OHB2] = head_b2[0];
    if (tid >= 96 && tid < 114) {                       // 18 rotation angles
        int k = tid - 96;
        float hw = q_weights[k] * 0.5f;
        lds[OCW + k] = __cosf(hw);
        lds[OSW + k] = __sinf(hw);
    }
    __syncthreads();

    const int b = blockIdx.x * 256 + tid;
    if (b >= n) return;

    // ---- load features (32 floats, 8x float4) ----
    float f[32];
    {
        const float4* fp = reinterpret_cast<const float4*>(features + (size_t)b * 32);
        #pragma unroll
        for (int k = 0; k < 8; ++k) {
            float4 v = fp[k];
            f[4*k+0] = v.x; f[4*k+1] = v.y; f[4*k+2] = v.z; f[4*k+3] = v.w;
        }
    }

    // ---- encoder layer 1: [32]->[16], GELU ----
    float h[16];
    #pragma unroll
    for (int o = 0; o < 16; ++o) h[o] = lds[OB1 + o];
    #pragma unroll
    for (int i = 0; i < 32; ++i) {
        const float fi = f[i];
        const float4* w = reinterpret_cast<const float4*>(&lds[OW1 + i * 16]);
        #pragma unroll
        for (int o4 = 0; o4 < 4; ++o4) {
            float4 wv = w[o4];
            h[o4*4+0] = fmaf(fi, wv.x, h[o4*4+0]);
            h[o4*4+1] = fmaf(fi, wv.y, h[o4*4+1]);
            h[o4*4+2] = fmaf(fi, wv.z, h[o4*4+2]);
            h[o4*4+3] = fmaf(fi, wv.w, h[o4*4+3]);
        }
    }
    #pragma unroll
    for (int o = 0; o < 16; ++o) h[o] = fast_gelu(h[o]);

    // ---- encoder layer 2: [16]->[6], tanh -> angles ----
    float c6[6], s6[6];
    #pragma unroll
    for (int o = 0; o < 6; ++o) {
        float a = lds[OB2 + o];
        #pragma unroll
        for (int i = 0; i < 16; ++i)
            a = fmaf(h[i], lds[OW2 + i * 6 + o], a);
        float half = fast_tanh(a) * 0.5f;
        c6[o] = __cosf(half);
        s6[o] = __sinf(half);
    }

    // ---- quantum circuit ----
    // flat amp index: qubit q <-> bit (5-q)  (qubit 0 most significant)

    // RY embedding from |0..0>: amp[j] = prod_q (bit_q ? s : c). Real state.
    float sr[64], si[64];
    sr[0] = 1.0f;
    #pragma unroll
    for (int qq = 0; qq < 6; ++qq) {        // process qubit 5-qq (stride 1<<qq)
        const int q = 5 - qq;
        const int len = 1 << qq;
        #pragma unroll
        for (int j = 0; j < len; ++j) {
            float v = sr[j];
            sr[j + len] = v * s6[q];
            sr[j]       = v * c6[q];
        }
    }
    #pragma unroll
    for (int j = 0; j < 64; ++j) si[j] = 0.0f;

    // entangler layers: RX on each wire then CNOT ring
    #pragma unroll
    for (int l = 0; l < 3; ++l) {
        #pragma unroll
        for (int q = 0; q < 6; ++q) {
            const float cw = lds[OCW + l * 6 + q];
            const float sw = lds[OSW + l * 6 + q];
            const int m = 1 << (5 - q);
            #pragma unroll
            for (int j = 0; j < 64; ++j) {
                if (j & m) continue;        // handle pair (j, j|m) once
                const int k = j | m;
                float r0 = sr[j], i0 = si[j], r1 = sr[k], i1 = si[k];
                // RX: a0' = cw*a0 - i*sw*a1 ; a1' = -i*sw*a0 + cw*a1
                sr[j] = fmaf(cw, r0,  sw * i1);
                si[j] = fmaf(cw, i0, -sw * r1);
                sr[k] = fmaf(cw, r1,  sw * i0);
                si[k] = fmaf(cw, i1, -sw * r0);
            }
        }
        // CNOT ring: control c, target (c+1)%6 — pure register permutation
        #pragma unroll
        for (int c = 0; c < 6; ++c) {
            const int t = (c + 1) % 6;
            const int cm = 1 << (5 - c);
            const int tm = 1 << (5 - t);
            #pragma unroll
            for (int j = 0; j < 64; ++j) {
                if ((j & cm) && !(j & tm)) {
                    const int k = j | tm;
                    float tr = sr[j]; sr[j] = sr[k]; sr[k] = tr;
                    float ti = si[j]; si[j] = si[k]; si[k] = ti;
                }
            }
        }
    }

    // ---- PauliZ expvals, shared fold tree (overwrite sr with probs) ----
    #pragma unroll
    for (int j = 0; j < 64; ++j) sr[j] = fmaf(sr[j], sr[j], si[j] * si[j]);

    float z[6];
    #pragma unroll
    for (int qq = 0; qq < 6; ++qq) {        // qubit 5-qq differs in adjacent idx
        const int q = 5 - qq;
        const int half = 32 >> qq;
        float acc = 0.0f;
        #pragma unroll
        for (int k = 0; k < half; ++k) acc += sr[2*k] - sr[2*k+1];
        z[q] = acc;
        #pragma unroll
        for (int k = 0; k < half; ++k) sr[k] = sr[2*k] + sr[2*k+1];
    }

    // ---- head: [6]->[16] GELU ->[1] ----
    float hh[16];
    #pragma unroll
    for (int o = 0; o < 16; ++o) hh[o] = lds[OHB1 + o];
    #pragma unroll
    for (int i = 0; i < 6; ++i) {
        const float zi = z[i];
        const float4* w = reinterpret_cast<const float4*>(&lds[OHW1 + i * 16]);
        #pragma unroll
        for (int o4 = 0; o4 < 4; ++o4) {
            float4 wv = w[o4];
            hh[o4*4+0] = fmaf(zi, wv.x, hh[o4*4+0]);
            hh[o4*4+1] = fmaf(zi, wv.y, hh[o4*4+1]);
            hh[o4*4+2] = fmaf(zi, wv.z, hh[o4*4+2]);
            hh[o4*4+3] = fmaf(zi, wv.w, hh[o4*4+3]);
        }
    }
    float r = lds[OHB2];
    #pragma unroll
    for (int o = 0; o < 16; ++o)
        r = fmaf(fast_gelu(hh[o]), lds[OHW2 + o], r);

    out[b] = baseline[b] + r;
}

extern "C" void kernel_launch(void* const* d_in, const int* in_sizes, int n_in,
                              void* d_out, int out_size, void* d_ws, size_t ws_size,
                              hipStream_t stream) {
    const float* features = (const float*)d_in[0];
    const float* baseline = (const float*)d_in[1];
    const float* enc_w1   = (const float*)d_in[2];
    const float* enc_b1   = (const float*)d_in[3];
    const float* enc_w2   = (const float*)d_in[4];
    const float* enc_b2   = (const float*)d_in[5];
    const float* q_weights= (const float*)d_in[6];
    const float* head_w1  = (const float*)d_in[7];
    const float* head_b1  = (const float*)d_in[8];
    const float* head_w2  = (const float*)d_in[9];
    const float* head_b2  = (const float*)d_in[10];
    float* out = (float*)d_out;

    const int n = in_sizes[0] / 32;          // B
    const int block = 256;
    const int grid = (n + block - 1) / block;
    qrr_kernel<<<grid, block, 0, stream>>>(features, baseline,
                                           enc_w1, enc_b1, enc_w2, enc_b2,
                                           q_weights, head_w1, head_b1,
                                           head_w2, head_b2, out, n);
}

// Round 3
// 22.129 us; speedup vs baseline: 6.3915x; 1.3012x over previous
//
#include <hip/hip_runtime.h>
#include <math.h>

// ---------------------------------------------------------------------------
// QuantumResidualRegressor: enc-MLP -> 6-qubit circuit sim -> head-MLP -> +baseline
// One thread per sample; 64 complex amps in registers as float2 ext-vectors.
// R3: pin VGPR budget to 256 (waves_per_eu(2,2)); merge RY+RX-layer0 into a
//     complex product-state build; packed-f32-friendly float2 gate math.
// ---------------------------------------------------------------------------

typedef float f32x2 __attribute__((ext_vector_type(2)));

// LDS layout (float offsets)
#define OW1   0      // 512  enc_w1 [32][16]
#define OB1   512    // 16   enc_b1
#define OW2   528    // 96   enc_w2 [16][6]
#define OB2   624    // 6    enc_b2
#define OHW1  632    // 96   head_w1 [6][16]
#define OHB1  728    // 16   head_b1
#define OHW2  744    // 16   head_w2 [16][1]
#define OHB2  760    // 1    head_b2
#define OG    764    // 72   18 gates x {cw, cw, sw, -sw}
#define LDSF  836

__device__ __forceinline__ float fast_tanh(float x) {
    float e = __expf(2.0f * x);
    return 1.0f - 2.0f / (1.0f + e);
}

__device__ __forceinline__ float fast_gelu(float x) {
    float x3 = x * x * x;
    float t  = fast_tanh(fmaf(0.044715f, x3, x) * 0.7978845608028654f);
    return 0.5f * x * (1.0f + t);
}

__global__ __launch_bounds__(256) __attribute__((amdgpu_waves_per_eu(2, 2)))
void qrr_kernel(const float* __restrict__ features,
                const float* __restrict__ baseline,
                const float* __restrict__ enc_w1,
                const float* __restrict__ enc_b1,
                const float* __restrict__ enc_w2,
                const float* __restrict__ enc_b2,
                const float* __restrict__ q_weights,
                const float* __restrict__ head_w1,
                const float* __restrict__ head_b1,
                const float* __restrict__ head_w2,
                const float* __restrict__ head_b2,
                float* __restrict__ out,
                int n)
{
    __shared__ __align__(16) float lds[LDSF];
    const int tid = threadIdx.x;

    // ---- cooperative weight preload (disjoint thread ranges in parallel) ----
    for (int k = tid; k < 512; k += 256) lds[OW1 + k] = enc_w1[k];
    if (tid < 16)                 lds[OB1 + tid] = enc_b1[tid];
    if (tid < 96)                 lds[OW2 + tid] = enc_w2[tid];
    if (tid < 6)                  lds[OB2 + tid] = enc_b2[tid];
    if (tid >= 128 && tid < 224)  lds[OHW1 + tid - 128] = head_w1[tid - 128];
    if (tid >= 224 && tid < 240)  lds[OHB1 + tid - 224] = head_b1[tid - 224];
    if (tid >= 240 && tid < 256)  lds[OHW2 + tid - 240] = head_w2[tid - 240];
    if (tid == 127)               lds[OHB2] = head_b2[0];
    if (tid >= 96 && tid < 114) {                       // 18 rotation gates
        int g = tid - 96;
        float hw = q_weights[g] * 0.5f;
        float cw = __cosf(hw), sw = __sinf(hw);
        lds[OG + 4*g + 0] = cw;
        lds[OG + 4*g + 1] = cw;
        lds[OG + 4*g + 2] = sw;
        lds[OG + 4*g + 3] = -sw;
    }
    __syncthreads();

    const int b = blockIdx.x * 256 + tid;
    if (b >= n) return;

    // ---- load features (32 floats, 8x float4) ----
    float f[32];
    {
        const float4* fp = reinterpret_cast<const float4*>(features + (size_t)b * 32);
        #pragma unroll
        for (int k = 0; k < 8; ++k) {
            float4 v = fp[k];
            f[4*k+0] = v.x; f[4*k+1] = v.y; f[4*k+2] = v.z; f[4*k+3] = v.w;
        }
    }

    // ---- encoder layer 1: [32]->[16], GELU ----
    float h[16];
    #pragma unroll
    for (int o = 0; o < 16; ++o) h[o] = lds[OB1 + o];
    #pragma unroll
    for (int i = 0; i < 32; ++i) {
        const float fi = f[i];
        const float4* w = reinterpret_cast<const float4*>(&lds[OW1 + i * 16]);
        #pragma unroll
        for (int o4 = 0; o4 < 4; ++o4) {
            float4 wv = w[o4];
            h[o4*4+0] = fmaf(fi, wv.x, h[o4*4+0]);
            h[o4*4+1] = fmaf(fi, wv.y, h[o4*4+1]);
            h[o4*4+2] = fmaf(fi, wv.z, h[o4*4+2]);
            h[o4*4+3] = fmaf(fi, wv.w, h[o4*4+3]);
        }
    }
    #pragma unroll
    for (int o = 0; o < 16; ++o) h[o] = fast_gelu(h[o]);

    // ---- encoder layer 2: [16]->[6], tanh -> angle halves (cos/sin) ----
    float c6[6], s6[6];
    #pragma unroll
    for (int o = 0; o < 6; ++o) {
        float a = lds[OB2 + o];
        #pragma unroll
        for (int i = 0; i < 16; ++i)
            a = fmaf(h[i], lds[OW2 + i * 6 + o], a);
        float half = fast_tanh(a) * 0.5f;
        c6[o] = __cosf(half);
        s6[o] = __sinf(half);
    }

    // ---- quantum circuit ----
    // flat amp index: qubit q <-> bit (5-q)  (qubit 0 most significant)
    // Layer 0 merged with RY embedding: per-qubit U = RX(w0q)*RY(ang_q) on |0>:
    //   v0 = (cw*ca, -sw*sa), v1 = (cw*sa, -sw*ca)
    // Build product state with complex mults: cmul(a, v) = fma(a.yy, vn, a.xx*v)
    //   where vn = (-v.y, v.x).
    f32x2 amp[64];
    {
        // qubit 5 seeds amps 0,1
        {
            const float cw = lds[OG + 4*5 + 0], sw = lds[OG + 4*5 + 2];
            float p1 = cw * c6[5], p2 = sw * s6[5];
            float p3 = cw * s6[5], p4 = sw * c6[5];
            amp[0] = (f32x2){p1, -p2};
            amp[1] = (f32x2){p3, -p4};
        }
        #pragma unroll
        for (int qq = 1; qq < 6; ++qq) {
            const int q = 5 - qq;
            const int len = 1 << qq;
            const float cw = lds[OG + 4*q + 0], sw = lds[OG + 4*q + 2];
            const float p1 = cw * c6[q], p2 = sw * s6[q];
            const float p3 = cw * s6[q], p4 = sw * c6[q];
            const f32x2 v0  = {p1, -p2}, v0n = {p2, p1};
            const f32x2 v1  = {p3, -p4}, v1n = {p4, p3};
            #pragma unroll
            for (int j = 0; j < len; ++j) {
                f32x2 a   = amp[j];
                f32x2 axx = __builtin_shufflevector(a, a, 0, 0);
                f32x2 ayy = __builtin_shufflevector(a, a, 1, 1);
                amp[j]       = __builtin_elementwise_fma(ayy, v0n, axx * v0);
                amp[j + len] = __builtin_elementwise_fma(ayy, v1n, axx * v1);
            }
        }
    }

    // CNOT ring after (merged) layer 0, then layers 1..2: RX + CNOT ring.
    #pragma unroll
    for (int l = 0; l < 3; ++l) {
        if (l > 0) {
            #pragma unroll
            for (int q = 0; q < 6; ++q) {
                const int g = l * 6 + q;
                const f32x2 cwv = *reinterpret_cast<const f32x2*>(&lds[OG + 4*g]);
                const f32x2 swv = *reinterpret_cast<const f32x2*>(&lds[OG + 4*g + 2]);
                const int m = 1 << (5 - q);
                #pragma unroll
                for (int j = 0; j < 64; ++j) {
                    if (j & m) continue;        // handle pair (j, j|m) once
                    const int k = j | m;
                    f32x2 a0 = amp[j], a1 = amp[k];
                    f32x2 t0 = swv * __builtin_shufflevector(a1, a1, 1, 0);
                    f32x2 t1 = swv * __builtin_shufflevector(a0, a0, 1, 0);
                    amp[j] = __builtin_elementwise_fma(cwv, a0, t0);
                    amp[k] = __builtin_elementwise_fma(cwv, a1, t1);
                }
            }
        }
        // CNOT ring: control c, target (c+1)%6 — pure register permutation
        #pragma unroll
        for (int c = 0; c < 6; ++c) {
            const int t = (c + 1) % 6;
            const int cm = 1 << (5 - c);
            const int tm = 1 << (5 - t);
            #pragma unroll
            for (int j = 0; j < 64; ++j) {
                if ((j & cm) && !(j & tm)) {
                    const int k = j | tm;
                    f32x2 tmp = amp[j]; amp[j] = amp[k]; amp[k] = tmp;
                }
            }
        }
    }

    // ---- PauliZ expvals, shared fold tree ----
    float p[64];
    #pragma unroll
    for (int j = 0; j < 64; ++j) {
        f32x2 t = amp[j] * amp[j];
        p[j] = t.x + t.y;
    }

    float z[6];
    #pragma unroll
    for (int qq = 0; qq < 6; ++qq) {        // qubit 5-qq differs in adjacent idx
        const int q = 5 - qq;
        const int half = 32 >> qq;
        float acc = 0.0f;
        #pragma unroll
        for (int k = 0; k < half; ++k) acc += p[2*k] - p[2*k+1];
        z[q] = acc;
        #pragma unroll
        for (int k = 0; k < half; ++k) p[k] = p[2*k] + p[2*k+1];
    }

    // ---- head: [6]->[16] GELU ->[1] ----
    float hh[16];
    #pragma unroll
    for (int o = 0; o < 16; ++o) hh[o] = lds[OHB1 + o];
    #pragma unroll
    for (int i = 0; i < 6; ++i) {
        const float zi = z[i];
        const float4* w = reinterpret_cast<const float4*>(&lds[OHW1 + i * 16]);
        #pragma unroll
        for (int o4 = 0; o4 < 4; ++o4) {
            float4 wv = w[o4];
            hh[o4*4+0] = fmaf(zi, wv.x, hh[o4*4+0]);
            hh[o4*4+1] = fmaf(zi, wv.y, hh[o4*4+1]);
            hh[o4*4+2] = fmaf(zi, wv.z, hh[o4*4+2]);
            hh[o4*4+3] = fmaf(zi, wv.w, hh[o4*4+3]);
        }
    }
    float r = lds[OHB2];
    #pragma unroll
    for (int o = 0; o < 16; ++o)
        r = fmaf(fast_gelu(hh[o]), lds[OHW2 + o], r);

    out[b] = baseline[b] + r;
}

extern "C" void kernel_launch(void* const* d_in, const int* in_sizes, int n_in,
                              void* d_out, int out_size, void* d_ws, size_t ws_size,
                              hipStream_t stream) {
    const float* features = (const float*)d_in[0];
    const float* baseline = (const float*)d_in[1];
    const float* enc_w1   = (const float*)d_in[2];
    const float* enc_b1   = (const float*)d_in[3];
    const float* enc_w2   = (const float*)d_in[4];
    const float* enc_b2   = (const float*)d_in[5];
    const float* q_weights= (const float*)d_in[6];
    const float* head_w1  = (const float*)d_in[7];
    const float* head_b1  = (const float*)d_in[8];
    const float* head_w2  = (const float*)d_in[9];
    const float* head_b2  = (const float*)d_in[10];
    float* out = (float*)d_out;

    const int n = in_sizes[0] / 32;          // B
    const int block = 256;
    const int grid = (n + block - 1) / block;
    qrr_kernel<<<grid, block, 0, stream>>>(features, baseline,
                                           enc_w1, enc_b1, enc_w2, enc_b2,
                                           q_weights, head_w1, head_b1,
                                           head_w2, head_b2, out, n);
}

// Round 4
// 19.568 us; speedup vs baseline: 7.2279x; 1.1309x over previous
//
#include <hip/hip_runtime.h>
#include <math.h>

// ---------------------------------------------------------------------------
// QuantumResidualRegressor R4: X-basis collapse of the circuit.
//   W = H^{\otimes 6}. W RX W = RZ (diagonal), W CNOT(c,t) W = CNOT(t,c)
//   (a permutation, GF(2)-linear map L). Whole circuit = Perm * diag(e^{i Phi})
//   on a REAL per-sample product state. Phi and the per-qubit pair-sums K~ are
//   wave-uniform -> precomputed per block. Per-sample circuit ~250 scalar ops,
//   no 64-amp register state.
// ---------------------------------------------------------------------------

typedef float f32x2 __attribute__((ext_vector_type(2)));

// LDS layout (float offsets)
#define OW1   0      // 512  enc_w1 [32][16]
#define OB1   512    // 16   enc_b1
#define OW2   528    // 96   enc_w2 [16][6]
#define OB2   624    // 6    enc_b2
#define OHW1  632    // 96   head_w1 [6][16]
#define OHB1  728    // 16   head_b1
#define OHW2  744    // 16   head_w2
#define OHB2  760    // 1    head_b2
#define OPHI  764    // 64   Phi_j (uniform phases)
#define OKT   828    // 48   K~[q][r] pair-cos sums
#define LDSF  876

// X-basis CNOT-ring permutation (one layer), as map on 6-bit indices.
// Original ring: CNOT(q, q+1 mod 6) applied q=0..5 sequentially.
// X basis: control/target swap -> b_{5-q} ^= b_{5-(q+1)%6}, sequential.
__host__ __device__ constexpr int Lmap(int j) {
    int b5=(j>>5)&1, b4=(j>>4)&1, b3=(j>>3)&1, b2=(j>>2)&1, b1=(j>>1)&1, b0=j&1;
    int o5=b5^b4, o4=b4^b3, o3=b3^b2, o2=b2^b1, o1=b1^b0, o0=b0^b5^b4; // last uses updated b5
    return (o5<<5)|(o4<<4)|(o3<<3)|(o2<<2)|(o1<<1)|o0;
}
__host__ __device__ constexpr int Linv(int j) {
    int o5=(j>>5)&1, o4=(j>>4)&1, o3=(j>>3)&1, o2=(j>>2)&1, o1=(j>>1)&1, o0=j&1;
    int b4 = o5^o4^o3^o2^o1^o0;
    int b5 = b4^o5;
    int b3 = b4^o4;
    int b2 = b3^o3;
    int b1 = b2^o2;
    int b0 = b1^o1;
    return (b5<<5)|(b4<<4)|(b3<<3)|(b2<<2)|(b1<<1)|b0;
}
__host__ __device__ constexpr int MPc(int q) {   // m'_q = L^{-3} (bit 5-q)
    int m = 1 << (5 - q);
    m = Linv(m); m = Linv(m); m = Linv(m);
    return m;
}
__host__ __device__ constexpr int popc6(int m) {
    int c = 0;
    for (int p = 0; p < 6; ++p) c += (m >> p) & 1;
    return c;
}

__device__ __forceinline__ float fast_tanh(float x) {
    float e = __expf(2.0f * x);
    return 1.0f - 2.0f / (1.0f + e);
}
__device__ __forceinline__ float fast_gelu(float x) {
    float x3 = x * x * x;
    float t  = fast_tanh(fmaf(0.044715f, x3, x) * 0.7978845608028654f);
    return 0.5f * x * (1.0f + t);
}

// z_q = c_q * sum_r K~[q][r] * prod_{free bits p} u2[p][bit_p(r)]
template<int Q>
__device__ __forceinline__ float zq_eval(const float (&u2)[6][2], const float (&u01)[6],
                                         const float* __restrict__ K) {
    constexpr int mp = MPc(Q);
    constexpr int F  = (~mp) & 63;
    constexpr int nf = 6 - popc6(mp);
    float cq = 1.0f;
    #pragma unroll
    for (int p = 0; p < 6; ++p) if ((mp >> p) & 1) cq *= u01[p];
    float acc = 0.0f;
    #pragma unroll
    for (int r = 0; r < (1 << nf); ++r) {
        float t = K[Q * 8 + r];
        int k = nf;
        #pragma unroll
        for (int p = 5; p >= 0; --p) if ((F >> p) & 1) { --k; t *= u2[p][(r >> k) & 1]; }
        acc += t;
    }
    return acc * cq;
}

__global__ __launch_bounds__(256)
void qrr_kernel(const float* __restrict__ features,
                const float* __restrict__ baseline,
                const float* __restrict__ enc_w1,
                const float* __restrict__ enc_b1,
                const float* __restrict__ enc_w2,
                const float* __restrict__ enc_b2,
                const float* __restrict__ q_weights,
                const float* __restrict__ head_w1,
                const float* __restrict__ head_b1,
                const float* __restrict__ head_w2,
                const float* __restrict__ head_b2,
                float* __restrict__ out,
                int n)
{
    __shared__ __align__(16) float lds[LDSF];
    const int tid = threadIdx.x;

    // ---- cooperative weight preload ----
    for (int k = tid; k < 512; k += 256) lds[OW1 + k] = enc_w1[k];
    if (tid < 16)                 lds[OB1 + tid] = enc_b1[tid];
    if (tid < 96)                 lds[OW2 + tid] = enc_w2[tid];
    if (tid < 6)                  lds[OB2 + tid] = enc_b2[tid];
    if (tid >= 128 && tid < 224)  lds[OHW1 + tid - 128] = head_w1[tid - 128];
    if (tid >= 224 && tid < 240)  lds[OHB1 + tid - 224] = head_b1[tid - 224];
    if (tid >= 240 && tid < 256)  lds[OHW2 + tid - 240] = head_w2[tid - 240];
    if (tid == 127)               lds[OHB2] = head_b2[0];

    // ---- stage A: Phi_j = sum_l phi_l(L^l j), phi_l(j)=sum_q th[l][q]*(b?+.5:-.5)
    if (tid < 64) {
        int jl = tid;
        float acc = 0.0f;
        for (int l = 0; l < 3; ++l) {
            for (int q = 0; q < 6; ++q)
                acc += q_weights[l * 6 + q] * (((jl >> (5 - q)) & 1) ? 0.5f : -0.5f);
            jl = Lmap(jl);
        }
        lds[OPHI + tid] = acc;
    }
    __syncthreads();

    // ---- stage B: K~[q][r] = (1/64) sum_{e configs of m' bits} cos(Phi_{j^m'}-Phi_j)
    if (tid < 48) {
        const int q = tid >> 3, r = tid & 7;
        const int mp = Linv(Linv(Linv(1 << (5 - q))));
        const int F  = (~mp) & 63;
        const int nf = __popc(F), pm = 6 - nf;
        float kv = 0.0f;
        if (r < (1 << nf)) {
            int jb = 0, k = nf;
            for (int p = 5; p >= 0; --p)
                if ((F >> p) & 1) { --k; if ((r >> k) & 1) jb |= 1 << p; }
            float s = 0.0f;
            for (int e = 0; e < (1 << pm); ++e) {
                int je = 0, kk = pm;
                for (int p = 5; p >= 0; --p)
                    if ((mp >> p) & 1) { --kk; if ((e >> kk) & 1) je |= 1 << p; }
                const int j0 = jb | je;
                s += cosf(lds[OPHI + (j0 ^ mp)] - lds[OPHI + j0]);
            }
            kv = s * (1.0f / 64.0f);
        }
        lds[OKT + q * 8 + r] = kv;
    }
    __syncthreads();

    const int b = blockIdx.x * 256 + tid;
    if (b >= n) return;

    // ---- load features ----
    float f[32];
    {
        const float4* fp = reinterpret_cast<const float4*>(features + (size_t)b * 32);
        #pragma unroll
        for (int k = 0; k < 8; ++k) {
            float4 v = fp[k];
            f[4*k+0] = v.x; f[4*k+1] = v.y; f[4*k+2] = v.z; f[4*k+3] = v.w;
        }
    }
    const float base = baseline[b];

    // ---- encoder L1: [32]->[16] GELU (packed f32x2) ----
    f32x2 h2[8];
    {
        const f32x2* bb = reinterpret_cast<const f32x2*>(&lds[OB1]);
        #pragma unroll
        for (int o = 0; o < 8; ++o) h2[o] = bb[o];
    }
    #pragma unroll
    for (int i = 0; i < 32; ++i) {
        const f32x2 fv = {f[i], f[i]};
        const f32x2* w = reinterpret_cast<const f32x2*>(&lds[OW1 + i * 16]);
        #pragma unroll
        for (int o = 0; o < 8; ++o)
            h2[o] = __builtin_elementwise_fma(fv, w[o], h2[o]);
    }
    float h[16];
    #pragma unroll
    for (int o = 0; o < 8; ++o) {
        h[2*o]   = fast_gelu(h2[o].x);
        h[2*o+1] = fast_gelu(h2[o].y);
    }

    // ---- encoder L2: [16]->[6] tanh -> per-qubit X-basis 2-vectors ----
    float u2[6][2], u01[6];
    #pragma unroll
    for (int q = 0; q < 6; ++q) {
        float a = lds[OB2 + q];
        #pragma unroll
        for (int i = 0; i < 16; ++i)
            a = fmaf(h[i], lds[OW2 + i * 6 + q], a);
        const float half = fast_tanh(a) * 0.5f;
        const float c = __cosf(half), s = __sinf(half);
        const float e0 = c + s, e1 = c - s;      // H*RY(a)|0>, 1/sqrt2 folded into K~
        const int p = 5 - q;                     // bit position of qubit q
        u2[p][0] = e0 * e0;
        u2[p][1] = e1 * e1;
        u01[p]   = e0 * e1;
    }

    // ---- expvals via factored quadratic forms ----
    float z[6];
    z[0] = zq_eval<0>(u2, u01, &lds[OKT]);
    z[1] = zq_eval<1>(u2, u01, &lds[OKT]);
    z[2] = zq_eval<2>(u2, u01, &lds[OKT]);
    z[3] = zq_eval<3>(u2, u01, &lds[OKT]);
    z[4] = zq_eval<4>(u2, u01, &lds[OKT]);
    z[5] = zq_eval<5>(u2, u01, &lds[OKT]);

    // ---- head: [6]->[16] GELU ->[1] ----
    f32x2 hh2[8];
    {
        const f32x2* bb = reinterpret_cast<const f32x2*>(&lds[OHB1]);
        #pragma unroll
        for (int o = 0; o < 8; ++o) hh2[o] = bb[o];
    }
    #pragma unroll
    for (int i = 0; i < 6; ++i) {
        const f32x2 zv = {z[i], z[i]};
        const f32x2* w = reinterpret_cast<const f32x2*>(&lds[OHW1 + i * 16]);
        #pragma unroll
        for (int o = 0; o < 8; ++o)
            hh2[o] = __builtin_elementwise_fma(zv, w[o], hh2[o]);
    }
    float r = lds[OHB2];
    #pragma unroll
    for (int o = 0; o < 8; ++o) {
        r = fmaf(fast_gelu(hh2[o].x), lds[OHW2 + 2*o],     r);
        r = fmaf(fast_gelu(hh2[o].y), lds[OHW2 + 2*o + 1], r);
    }

    out[b] = base + r;
}

extern "C" void kernel_launch(void* const* d_in, const int* in_sizes, int n_in,
                              void* d_out, int out_size, void* d_ws, size_t ws_size,
                              hipStream_t stream) {
    const float* features = (const float*)d_in[0];
    const float* baseline = (const float*)d_in[1];
    const float* enc_w1   = (const float*)d_in[2];
    const float* enc_b1   = (const float*)d_in[3];
    const float* enc_w2   = (const float*)d_in[4];
    const float* enc_b2   = (const float*)d_in[5];
    const float* q_weights= (const float*)d_in[6];
    const float* head_w1  = (const float*)d_in[7];
    const float* head_b1  = (const float*)d_in[8];
    const float* head_w2  = (const float*)d_in[9];
    const float* head_b2  = (const float*)d_in[10];
    float* out = (float*)d_out;

    const int n = in_sizes[0] / 32;          // B
    const int block = 256;
    const int grid = (n + block - 1) / block;
    qrr_kernel<<<grid, block, 0, stream>>>(features, baseline,
                                           enc_w1, enc_b1, enc_w2, enc_b2,
                                           q_weights, head_w1, head_b1,
                                           head_w2, head_b2, out, n);
}

// Round 5
// 19.279 us; speedup vs baseline: 7.3361x; 1.0150x over previous
//
#include <hip/hip_runtime.h>
#include <math.h>

// ---------------------------------------------------------------------------
// QuantumResidualRegressor R5: latency-bound fix.
//   - prep kernel computes the wave-uniform K~[6][8] (X-basis collapsed
//     circuit kernel) once into d_ws.
//   - main kernel has NO LDS, NO syncthreads; all weights read via uniform
//     (compile-time) indices -> compiler scalarizes to s_load / SGPR operands
//     on the scalar pipe. Vector memory = features + baseline + out only.
// ---------------------------------------------------------------------------

typedef float f32x2 __attribute__((ext_vector_type(2)));

// X-basis CNOT-ring permutation (one layer) on 6-bit indices.
__host__ __device__ constexpr int Lmap(int j) {
    int b5=(j>>5)&1, b4=(j>>4)&1, b3=(j>>3)&1, b2=(j>>2)&1, b1=(j>>1)&1, b0=j&1;
    int o5=b5^b4, o4=b4^b3, o3=b3^b2, o2=b2^b1, o1=b1^b0, o0=b0^b5^b4;
    return (o5<<5)|(o4<<4)|(o3<<3)|(o2<<2)|(o1<<1)|o0;
}
__host__ __device__ constexpr int Linv(int j) {
    int o5=(j>>5)&1, o4=(j>>4)&1, o3=(j>>3)&1, o2=(j>>2)&1, o1=(j>>1)&1, o0=j&1;
    int b4 = o5^o4^o3^o2^o1^o0;
    int b5 = b4^o5;
    int b3 = b4^o4;
    int b2 = b3^o3;
    int b1 = b2^o2;
    int b0 = b1^o1;
    return (b5<<5)|(b4<<4)|(b3<<3)|(b2<<2)|(b1<<1)|b0;
}
__host__ __device__ constexpr int MPc(int q) {   // m'_q = L^{-3} (bit 5-q)
    int m = 1 << (5 - q);
    m = Linv(m); m = Linv(m); m = Linv(m);
    return m;
}
__host__ __device__ constexpr int popc6(int m) {
    int c = 0;
    for (int p = 0; p < 6; ++p) c += (m >> p) & 1;
    return c;
}

__device__ __forceinline__ float fast_tanh(float x) {
    float e = __expf(2.0f * x);
    return 1.0f - 2.0f / (1.0f + e);
}
__device__ __forceinline__ float fast_gelu(float x) {
    float x3 = x * x * x;
    float t  = fast_tanh(fmaf(0.044715f, x3, x) * 0.7978845608028654f);
    return 0.5f * x * (1.0f + t);
}

// ---------------- prep: K~[q][r] from q_weights (uniform) -------------------
__global__ void prep_kernel(const float* __restrict__ q_weights,
                            float* __restrict__ Kt)
{
    __shared__ float phi[64];
    const int tid = threadIdx.x;          // 64 threads
    {
        int jl = tid;
        float acc = 0.0f;
        for (int l = 0; l < 3; ++l) {
            for (int q = 0; q < 6; ++q)
                acc += q_weights[l * 6 + q] * (((jl >> (5 - q)) & 1) ? 0.5f : -0.5f);
            jl = Lmap(jl);
        }
        phi[tid] = acc;
    }
    __syncthreads();
    if (tid < 48) {
        const int q = tid >> 3, r = tid & 7;
        const int mp = Linv(Linv(Linv(1 << (5 - q))));
        const int F  = (~mp) & 63;
        const int nf = __popc(F), pm = 6 - nf;
        float kv = 0.0f;
        if (r < (1 << nf)) {
            int jb = 0, k = nf;
            for (int p = 5; p >= 0; --p)
                if ((F >> p) & 1) { --k; if ((r >> k) & 1) jb |= 1 << p; }
            float s = 0.0f;
            for (int e = 0; e < (1 << pm); ++e) {
                int je = 0, kk = pm;
                for (int p = 5; p >= 0; --p)
                    if ((mp >> p) & 1) { --kk; if ((e >> kk) & 1) je |= 1 << p; }
                const int j0 = jb | je;
                s += cosf(phi[j0 ^ mp] - phi[j0]);
            }
            kv = s * (1.0f / 64.0f);
        }
        Kt[tid] = kv;
    }
}

// z_q = c_q * sum_r K~[q][r] * prod_{free bits p} u2[p][bit_p(r)]
template<int Q>
__device__ __forceinline__ float zq_eval(const float (&u2)[6][2], const float (&u01)[6],
                                         const float* __restrict__ K) {
    constexpr int mp = MPc(Q);
    constexpr int F  = (~mp) & 63;
    constexpr int nf = 6 - popc6(mp);
    float cq = 1.0f;
    #pragma unroll
    for (int p = 0; p < 6; ++p) if ((mp >> p) & 1) cq *= u01[p];
    float acc = 0.0f;
    #pragma unroll
    for (int r = 0; r < (1 << nf); ++r) {
        float t = K[Q * 8 + r];
        int k = nf;
        #pragma unroll
        for (int p = 5; p >= 0; --p) if ((F >> p) & 1) { --k; t *= u2[p][(r >> k) & 1]; }
        acc += t;
    }
    return acc * cq;
}

// ---------------- main: one thread per sample, registers only ---------------
__global__ __launch_bounds__(256) __attribute__((amdgpu_waves_per_eu(2, 2)))
void qrr_kernel(const float* __restrict__ features,
                const float* __restrict__ baseline,
                const float* __restrict__ enc_w1,
                const float* __restrict__ enc_b1,
                const float* __restrict__ enc_w2,
                const float* __restrict__ enc_b2,
                const float* __restrict__ head_w1,
                const float* __restrict__ head_b1,
                const float* __restrict__ head_w2,
                const float* __restrict__ head_b2,
                const float* __restrict__ Kt,
                float* __restrict__ out,
                int n)
{
    const int b = blockIdx.x * 256 + threadIdx.x;
    if (b >= n) return;

    // ---- features (8x dwordx4, coalesced) ----
    float f[32];
    {
        const float4* fp = reinterpret_cast<const float4*>(features + (size_t)b * 32);
        #pragma unroll
        for (int k = 0; k < 8; ++k) {
            float4 v = fp[k];
            f[4*k+0] = v.x; f[4*k+1] = v.y; f[4*k+2] = v.z; f[4*k+3] = v.w;
        }
    }
    const float base = baseline[b];

    // ---- encoder L1: [32]->[16] GELU; weights via uniform s_load ----
    f32x2 h2[8];
    {
        const f32x2* bb = reinterpret_cast<const f32x2*>(enc_b1);
        #pragma unroll
        for (int o = 0; o < 8; ++o) h2[o] = bb[o];
    }
    #pragma unroll
    for (int i = 0; i < 32; ++i) {
        const f32x2 fv = {f[i], f[i]};
        const f32x2* w = reinterpret_cast<const f32x2*>(enc_w1 + i * 16);
        #pragma unroll
        for (int o = 0; o < 8; ++o)
            h2[o] = __builtin_elementwise_fma(fv, w[o], h2[o]);
    }
    float h[16];
    #pragma unroll
    for (int o = 0; o < 8; ++o) {
        h[2*o]   = fast_gelu(h2[o].x);
        h[2*o+1] = fast_gelu(h2[o].y);
    }

    // ---- encoder L2: [16]->[6] tanh -> per-qubit X-basis 2-vectors ----
    float u2[6][2], u01[6];
    #pragma unroll
    for (int q = 0; q < 6; ++q) {
        float a = enc_b2[q];
        #pragma unroll
        for (int i = 0; i < 16; ++i)
            a = fmaf(h[i], enc_w2[i * 6 + q], a);
        const float half = fast_tanh(a) * 0.5f;
        float s, c;
        __sincosf(half, &s, &c);
        const float e0 = c + s, e1 = c - s;   // H*RY(a)|0>, 1/sqrt2 folded into K~
        const int p = 5 - q;                  // bit position of qubit q
        u2[p][0] = e0 * e0;
        u2[p][1] = e1 * e1;
        u01[p]   = e0 * e1;
    }

    // ---- expvals via factored quadratic forms (K~ uniform via s_load) ----
    float z[6];
    z[0] = zq_eval<0>(u2, u01, Kt);
    z[1] = zq_eval<1>(u2, u01, Kt);
    z[2] = zq_eval<2>(u2, u01, Kt);
    z[3] = zq_eval<3>(u2, u01, Kt);
    z[4] = zq_eval<4>(u2, u01, Kt);
    z[5] = zq_eval<5>(u2, u01, Kt);

    // ---- head: [6]->[16] GELU ->[1] ----
    f32x2 hh2[8];
    {
        const f32x2* bb = reinterpret_cast<const f32x2*>(head_b1);
        #pragma unroll
        for (int o = 0; o < 8; ++o) hh2[o] = bb[o];
    }
    #pragma unroll
    for (int i = 0; i < 6; ++i) {
        const f32x2 zv = {z[i], z[i]};
        const f32x2* w = reinterpret_cast<const f32x2*>(head_w1 + i * 16);
        #pragma unroll
        for (int o = 0; o < 8; ++o)
            hh2[o] = __builtin_elementwise_fma(zv, w[o], hh2[o]);
    }
    float r = head_b2[0];
    #pragma unroll
    for (int o = 0; o < 8; ++o) {
        r = fmaf(fast_gelu(hh2[o].x), head_w2[2*o],     r);
        r = fmaf(fast_gelu(hh2[o].y), head_w2[2*o + 1], r);
    }

    out[b] = base + r;
}

extern "C" void kernel_launch(void* const* d_in, const int* in_sizes, int n_in,
                              void* d_out, int out_size, void* d_ws, size_t ws_size,
                              hipStream_t stream) {
    const float* features = (const float*)d_in[0];
    const float* baseline = (const float*)d_in[1];
    const float* enc_w1   = (const float*)d_in[2];
    const float* enc_b1   = (const float*)d_in[3];
    const float* enc_w2   = (const float*)d_in[4];
    const float* enc_b2   = (const float*)d_in[5];
    const float* q_weights= (const float*)d_in[6];
    const float* head_w1  = (const float*)d_in[7];
    const float* head_b1  = (const float*)d_in[8];
    const float* head_w2  = (const float*)d_in[9];
    const float* head_b2  = (const float*)d_in[10];
    float* out = (float*)d_out;
    float* Kt  = (float*)d_ws;               // 48 floats

    prep_kernel<<<1, 64, 0, stream>>>(q_weights, Kt);

    const int n = in_sizes[0] / 32;          // B
    const int block = 256;
    const int grid = (n + block - 1) / block;
    qrr_kernel<<<grid, block, 0, stream>>>(features, baseline,
                                           enc_w1, enc_b1, enc_w2, enc_b2,
                                           head_w1, head_b1, head_w2, head_b2,
                                           Kt, out, n);
}

// Round 6
// 15.530 us; speedup vs baseline: 9.1070x; 1.2414x over previous
//
#include <hip/hip_runtime.h>
#include <math.h>

// ---------------------------------------------------------------------------
// QuantumResidualRegressor R6: single kernel.
//   X-basis collapsed circuit (validated R4/R5): z_q are factored quadratic
//   forms with wave-uniform kernel K~[6][8], computed per-block in LDS then
//   pulled into registers. Weights via uniform s_load. All divisions ->
//   v_rcp_f32; half-angle sincos removed via 1±sin(w), cos(w) identities.
// ---------------------------------------------------------------------------

typedef float f32x2 __attribute__((ext_vector_type(2)));

// X-basis CNOT-ring permutation (one layer) on 6-bit indices.
__host__ __device__ constexpr int Lmap(int j) {
    int b5=(j>>5)&1, b4=(j>>4)&1, b3=(j>>3)&1, b2=(j>>2)&1, b1=(j>>1)&1, b0=j&1;
    int o5=b5^b4, o4=b4^b3, o3=b3^b2, o2=b2^b1, o1=b1^b0, o0=b0^b5^b4;
    return (o5<<5)|(o4<<4)|(o3<<3)|(o2<<2)|(o1<<1)|o0;
}
__host__ __device__ constexpr int Linv(int j) {
    int o5=(j>>5)&1, o4=(j>>4)&1, o3=(j>>3)&1, o2=(j>>2)&1, o1=(j>>1)&1, o0=j&1;
    int b4 = o5^o4^o3^o2^o1^o0;
    int b5 = b4^o5;
    int b3 = b4^o4;
    int b2 = b3^o3;
    int b1 = b2^o2;
    int b0 = b1^o1;
    return (b5<<5)|(b4<<4)|(b3<<3)|(b2<<2)|(b1<<1)|b0;
}
__host__ __device__ constexpr int MPc(int q) {   // m'_q = L^{-3} (bit 5-q)
    int m = 1 << (5 - q);
    m = Linv(m); m = Linv(m); m = Linv(m);
    return m;
}
__host__ __device__ constexpr int popc6(int m) {
    int c = 0;
    for (int p = 0; p < 6; ++p) c += (m >> p) & 1;
    return c;
}

__device__ __forceinline__ float fast_rcp(float x) { return __builtin_amdgcn_rcpf(x); }

__device__ __forceinline__ float fast_tanh(float x) {
    // tanh(x) = 1 - 2/(1+e^{2x});  rcp is v_rcp_f32 (1 instr)
    float e = __expf(2.0f * x);
    return fmaf(-2.0f, fast_rcp(1.0f + e), 1.0f);
}
__device__ __forceinline__ float fast_gelu(float x) {
    float x3 = x * x * x;
    float t  = fast_tanh(fmaf(0.044715f, x3, x) * 0.7978845608028654f);
    return 0.5f * x * (1.0f + t);
}

// z_q = c_q * sum_r K[q*8+r] * prod_{free bits p} u2[p][bit_p(r)]
template<int Q>
__device__ __forceinline__ float zq_eval(const float (&u2)[6][2], const float (&u01)[6],
                                         const float (&K)[48]) {
    constexpr int mp = MPc(Q);
    constexpr int F  = (~mp) & 63;
    constexpr int nf = 6 - popc6(mp);
    float cq = 1.0f;
    #pragma unroll
    for (int p = 0; p < 6; ++p) if ((mp >> p) & 1) cq *= u01[p];
    float acc = 0.0f;
    #pragma unroll
    for (int r = 0; r < (1 << nf); ++r) {
        float t = K[Q * 8 + r];
        int k = nf;
        #pragma unroll
        for (int p = 5; p >= 0; --p) if ((F >> p) & 1) { --k; t *= u2[p][(r >> k) & 1]; }
        acc += t;
    }
    return acc * cq;
}

__global__ __launch_bounds__(256) __attribute__((amdgpu_waves_per_eu(2, 2)))
void qrr_kernel(const float* __restrict__ features,
                const float* __restrict__ baseline,
                const float* __restrict__ enc_w1,
                const float* __restrict__ enc_b1,
                const float* __restrict__ enc_w2,
                const float* __restrict__ enc_b2,
                const float* __restrict__ q_weights,
                const float* __restrict__ head_w1,
                const float* __restrict__ head_b1,
                const float* __restrict__ head_w2,
                const float* __restrict__ head_b2,
                float* __restrict__ out,
                int n)
{
    __shared__ float phi[64];
    __shared__ __align__(16) float KTs[48];
    const int tid = threadIdx.x;

    // ---- stage A: uniform phases Phi_j (threads 0..63) ----
    if (tid < 64) {
        int jl = tid;
        float acc = 0.0f;
        for (int l = 0; l < 3; ++l) {
            for (int q = 0; q < 6; ++q)
                acc += q_weights[l * 6 + q] * (((jl >> (5 - q)) & 1) ? 0.5f : -0.5f);
            jl = Lmap(jl);
        }
        phi[tid] = acc;
    }
    __syncthreads();

    // ---- stage B: K~[q][r] (threads 0..47) ----
    if (tid < 48) {
        const int q = tid >> 3, r = tid & 7;
        const int mp = Linv(Linv(Linv(1 << (5 - q))));
        const int F  = (~mp) & 63;
        const int nf = __popc(F), pm = 6 - nf;
        float kv = 0.0f;
        if (r < (1 << nf)) {
            int jb = 0, k = nf;
            for (int p = 5; p >= 0; --p)
                if ((F >> p) & 1) { --k; if ((r >> k) & 1) jb |= 1 << p; }
            float s = 0.0f;
            for (int e = 0; e < (1 << pm); ++e) {
                int je = 0, kk = pm;
                for (int p = 5; p >= 0; --p)
                    if ((mp >> p) & 1) { --kk; if ((e >> kk) & 1) je |= 1 << p; }
                const int j0 = jb | je;
                s += __cosf(phi[j0 ^ mp] - phi[j0]);
            }
            kv = s * (1.0f / 64.0f);
        }
        KTs[tid] = kv;
    }
    __syncthreads();

    // ---- pull K~ into registers (12x ds_read_b128, constant offsets) ----
    float K[48];
    {
        const float4* kp = reinterpret_cast<const float4*>(KTs);
        #pragma unroll
        for (int i = 0; i < 12; ++i) {
            float4 v = kp[i];
            K[4*i+0] = v.x; K[4*i+1] = v.y; K[4*i+2] = v.z; K[4*i+3] = v.w;
        }
    }

    const int b = blockIdx.x * 256 + tid;
    if (b >= n) return;

    // ---- features (8x dwordx4, coalesced) ----
    float f[32];
    {
        const float4* fp = reinterpret_cast<const float4*>(features + (size_t)b * 32);
        #pragma unroll
        for (int k = 0; k < 8; ++k) {
            float4 v = fp[k];
            f[4*k+0] = v.x; f[4*k+1] = v.y; f[4*k+2] = v.z; f[4*k+3] = v.w;
        }
    }
    const float base = baseline[b];

    // ---- encoder L1: [32]->[16] GELU; weights via uniform s_load ----
    f32x2 h2[8];
    {
        const f32x2* bb = reinterpret_cast<const f32x2*>(enc_b1);
        #pragma unroll
        for (int o = 0; o < 8; ++o) h2[o] = bb[o];
    }
    #pragma unroll
    for (int i = 0; i < 32; ++i) {
        const f32x2 fv = {f[i], f[i]};
        const f32x2* w = reinterpret_cast<const f32x2*>(enc_w1 + i * 16);
        #pragma unroll
        for (int o = 0; o < 8; ++o)
            h2[o] = __builtin_elementwise_fma(fv, w[o], h2[o]);
    }
    float h[16];
    #pragma unroll
    for (int o = 0; o < 8; ++o) {
        h[2*o]   = fast_gelu(h2[o].x);
        h[2*o+1] = fast_gelu(h2[o].y);
    }

    // ---- encoder L2: [16]->[6] tanh(a)=w -> u2 = 1±sin(w), u01 = cos(w) ----
    float u2[6][2], u01[6];
    #pragma unroll
    for (int q = 0; q < 6; ++q) {
        float a = enc_b2[q];
        #pragma unroll
        for (int i = 0; i < 16; ++i)
            a = fmaf(h[i], enc_w2[i * 6 + q], a);
        const float w = fast_tanh(a);
        float sn, cs;
        __sincosf(w, &sn, &cs);
        const int p = 5 - q;                  // bit position of qubit q
        u2[p][0] = 1.0f + sn;
        u2[p][1] = 1.0f - sn;
        u01[p]   = cs;
    }

    // ---- expvals via factored quadratic forms (K in registers) ----
    float z[6];
    z[0] = zq_eval<0>(u2, u01, K);
    z[1] = zq_eval<1>(u2, u01, K);
    z[2] = zq_eval<2>(u2, u01, K);
    z[3] = zq_eval<3>(u2, u01, K);
    z[4] = zq_eval<4>(u2, u01, K);
    z[5] = zq_eval<5>(u2, u01, K);

    // ---- head: [6]->[16] GELU ->[1] ----
    f32x2 hh2[8];
    {
        const f32x2* bb = reinterpret_cast<const f32x2*>(head_b1);
        #pragma unroll
        for (int o = 0; o < 8; ++o) hh2[o] = bb[o];
    }
    #pragma unroll
    for (int i = 0; i < 6; ++i) {
        const f32x2 zv = {z[i], z[i]};
        const f32x2* w = reinterpret_cast<const f32x2*>(head_w1 + i * 16);
        #pragma unroll
        for (int o = 0; o < 8; ++o)
            hh2[o] = __builtin_elementwise_fma(zv, w[o], hh2[o]);
    }
    float r = head_b2[0];
    #pragma unroll
    for (int o = 0; o < 8; ++o) {
        r = fmaf(fast_gelu(hh2[o].x), head_w2[2*o],     r);
        r = fmaf(fast_gelu(hh2[o].y), head_w2[2*o + 1], r);
    }

    out[b] = base + r;
}

extern "C" void kernel_launch(void* const* d_in, const int* in_sizes, int n_in,
                              void* d_out, int out_size, void* d_ws, size_t ws_size,
                              hipStream_t stream) {
    const float* features = (const float*)d_in[0];
    const float* baseline = (const float*)d_in[1];
    const float* enc_w1   = (const float*)d_in[2];
    const float* enc_b1   = (const float*)d_in[3];
    const float* enc_w2   = (const float*)d_in[4];
    const float* enc_b2   = (const float*)d_in[5];
    const float* q_weights= (const float*)d_in[6];
    const float* head_w1  = (const float*)d_in[7];
    const float* head_b1  = (const float*)d_in[8];
    const float* head_w2  = (const float*)d_in[9];
    const float* head_b2  = (const float*)d_in[10];
    float* out = (float*)d_out;

    const int n = in_sizes[0] / 32;          // B
    const int block = 256;
    const int grid = (n + block - 1) / block;
    qrr_kernel<<<grid, block, 0, stream>>>(features, baseline,
                                           enc_w1, enc_b1, enc_w2, enc_b2,
                                           q_weights,
                                           head_w1, head_b1, head_w2, head_b2,
                                           out, n);
}